// Round 2
// baseline (154.161 us; speedup 1.0000x reference)
//
#include <hip/hip_runtime.h>
#include <hip/hip_bf16.h>

#define B_ 32
#define D_ 64
#define N_ 254
#define L_ 16
#define H_ 128
#define P_ 96
#define PAIRS (B_*D_)    // 2048
#define XPAIR (N_*L_)    // 4064 floats per (b,d) pair
#define OUT0  (B_*P_*D_) // 196608 floats (output 0)

// ws layout (floats):
//   0    : K[128]      = 254*b_enc + sum_n pos[n]
//   128  : M[256]      = W_enc W_enc^T  (16x16, [l1*16+l2])
//   384  : vK[16]      = W_enc @ K
//   400  : bW[16]      = W_enc @ b_enc
//   416  : bK[1]       = b_enc . K
//   432  : G[254*16]   = pos @ W_enc^T  ([n*16+l])
//   4496 : pK[254]     = pos @ K

__global__ void pre1(const float* __restrict__ W_enc, const float* __restrict__ b_enc,
                     const float* __restrict__ pos, float* __restrict__ ws) {
    int t = threadIdx.x;  // 256 threads
    __shared__ float Ks[128];
    if (t < 128) {
        float s = 0.f;
        for (int n = 0; n < N_; n++) s += pos[n * H_ + t];
        float k = 254.f * b_enc[t] + s;
        ws[t] = k;      // K
        Ks[t] = k;
    }
    __syncthreads();
    // M[l1*16+l2] = W_enc[l1,:] . W_enc[l2,:]
    {
        int l1 = t >> 4, l2 = t & 15;
        float s = 0.f;
        for (int h = 0; h < H_; h++)
            s += W_enc[l1 * H_ + h] * W_enc[l2 * H_ + h];
        ws[128 + t] = s;
    }
    if (t < 16) {
        float s1 = 0.f, s2 = 0.f;
        for (int h = 0; h < H_; h++) {
            float w = W_enc[t * H_ + h];
            s1 += w * Ks[h];
            s2 += w * b_enc[h];
        }
        ws[384 + t] = s1;  // vK
        ws[400 + t] = s2;  // bW
    }
    if (t == 16) {
        float s = 0.f;
        for (int h = 0; h < H_; h++) s += b_enc[h] * Ks[h];
        ws[416] = s;       // bK
    }
}

__global__ void pre2(const float* __restrict__ W_enc, const float* __restrict__ pos,
                     float* __restrict__ ws) {
    int n = blockIdx.x;       // 254 blocks
    int lane = threadIdx.x;   // 64 threads = 1 wave
    float pa = pos[n * H_ + lane];
    float pb = pos[n * H_ + 64 + lane];
    #pragma unroll
    for (int l = 0; l < L_; l++) {
        float v = pa * W_enc[l * H_ + lane] + pb * W_enc[l * H_ + 64 + lane];
        for (int off = 32; off; off >>= 1) v += __shfl_down(v, off);
        if (lane == 0) ws[432 + n * 16 + l] = v;   // G
    }
    float v = pa * ws[lane] + pb * ws[lane + 64];
    for (int off = 32; off; off >>= 1) v += __shfl_down(v, off);
    if (lane == 0) ws[4496 + n] = v;               // pK
}

__global__ __launch_bounds__(256) void mainker(const float* __restrict__ x,
                                               const float* __restrict__ W1,
                                               const float* __restrict__ b1,
                                               const float* __restrict__ W2,
                                               const float* __restrict__ b2,
                                               const float* __restrict__ ws,
                                               float* __restrict__ out) {
    __shared__ float xf[N_ * 17 + 16];  // stride-17 padded x tile
    __shared__ float red[256];
    __shared__ float scoreS[N_];
    __shared__ float xsS[16], vS[16], pooledS[16], hS[128];
    __shared__ float s0S, denomS;

    int t  = threadIdx.x;
    int bd = blockIdx.x;   // b*64 + d

    // ---- load x slice (4064 floats = 1016 float4), write copy, unpack to LDS ----
    const float4* xv = (const float4*)(x + (size_t)bd * XPAIR);
    float4*       cv = (float4*)(out + OUT0) + (size_t)bd * (XPAIR / 4);
    for (int i = t; i < XPAIR / 4; i += 256) {
        float4 v = xv[i];
        cv[i] = v;
        int idx = i * 4;                 // idx%16 in {0,4,8,12}: no row crossing
        int n = idx >> 4, l = idx & 15;
        float* p = &xf[n * 17 + l];
        p[0] = v.x; p[1] = v.y; p[2] = v.z; p[3] = v.w;
    }
    __syncthreads();

    // ---- xs[l] = sum_n x[n,l] ----
    {
        int l = t & 15, g = t >> 4;
        float s = 0.f;
        for (int n = g; n < N_; n += 16) s += xf[n * 17 + l];
        red[t] = s;
    }
    __syncthreads();
    if (t < 16) {
        float s = 0.f;
        for (int g = 0; g < 16; g++) s += red[g * 16 + t];
        xsS[t] = s;
    }
    __syncthreads();

    // ---- v[l] = vK[l] + (M^T xs)[l];  s0 = bK + xs.bW ----
    if (t < 16) {
        float s = ws[384 + t];
        for (int l2 = 0; l2 < 16; l2++) s += xsS[l2] * ws[128 + l2 * 16 + t];
        vS[t] = s;
    } else if (t == 16) {
        float s = ws[416];
        for (int l = 0; l < 16; l++) s += xsS[l] * ws[400 + l];
        s0S = s;
    }
    __syncthreads();

    // ---- score[n] = s0 + pK[n] + x[n].v + xs.G[n] ----
    if (t < N_) {
        const float* Gn = ws + 432 + t * 16;
        float s = s0S + ws[4496 + t];
        #pragma unroll
        for (int l = 0; l < 16; l++) s += xf[t * 17 + l] * vS[l] + xsS[l] * Gn[l];
        scoreS[t] = s;
    }
    __syncthreads();

    // ---- denom = sum |score| (wave 0) ----
    if (t < 64) {
        float s = 0.f;
        for (int n = t; n < N_; n += 64) s += fabsf(scoreS[n]);
        for (int off = 32; off; off >>= 1) s += __shfl_down(s, off);
        if (t == 0) denomS = s;
    }
    __syncthreads();
    float inv = 1.0f / denomS;

    // ---- pooled[l] = (sum_n x[n,l]*score[n]) / denom ----
    {
        int l = t & 15, g = t >> 4;
        float s = 0.f;
        for (int n = g; n < N_; n += 16) s += xf[n * 17 + l] * scoreS[n];
        red[t] = s;
    }
    __syncthreads();
    if (t < 16) {
        float s = 0.f;
        for (int g = 0; g < 16; g++) s += red[g * 16 + t];
        pooledS[t] = s * inv;
    }
    __syncthreads();

    // ---- h = leaky_relu(pooled @ W1 + b1, 0.2) ----
    if (t < 128) {
        float s = b1[t];
        #pragma unroll
        for (int l = 0; l < 16; l++) s += pooledS[l] * W1[l * H_ + t];
        hS[t] = s > 0.f ? s : 0.2f * s;
    }
    __syncthreads();

    // ---- out0[b, p, d] = h @ W2 + b2 ----
    if (t < 96) {
        float s = b2[t];
        for (int j = 0; j < 128; j++) s += hS[j] * W2[j * P_ + t];
        int b = bd >> 6, d = bd & 63;
        out[b * (P_ * D_) + t * D_ + d] = s;
    }
}

extern "C" void kernel_launch(void* const* d_in, const int* in_sizes, int n_in,
                              void* d_out, int out_size, void* d_ws, size_t ws_size,
                              hipStream_t stream) {
    const float* x     = (const float*)d_in[0];
    const float* W_enc = (const float*)d_in[1];
    const float* b_enc = (const float*)d_in[2];
    const float* W1    = (const float*)d_in[3];
    const float* b1    = (const float*)d_in[4];
    const float* W2    = (const float*)d_in[5];
    const float* b2    = (const float*)d_in[6];
    const float* pos   = (const float*)d_in[7];
    float* ws  = (float*)d_ws;
    float* out = (float*)d_out;

    hipLaunchKernelGGL(pre1, dim3(1), dim3(256), 0, stream, W_enc, b_enc, pos, ws);
    hipLaunchKernelGGL(pre2, dim3(254), dim3(64), 0, stream, W_enc, pos, ws);
    hipLaunchKernelGGL(mainker, dim3(PAIRS), dim3(256), 0, stream, x, W1, b1, W2, b2, ws, out);
}

// Round 3
// 119.300 us; speedup vs baseline: 1.2922x; 1.2922x over previous
//
#include <hip/hip_runtime.h>
#include <hip/hip_bf16.h>

#define B_ 32
#define D_ 64
#define N_ 254
#define L_ 16
#define H_ 128
#define P_ 96
#define PAIRS (B_*D_)    // 2048
#define XPAIR (N_*L_)    // 4064 floats per (b,d) pair
#define OUT0  (B_*P_*D_) // 196608 floats (output 0)

// ws layout (floats):
//   128  : M[256]      = W_enc W_enc^T  (16x16, [l1*16+l2])
//   384  : vK[16]      = W_enc @ K,  K = 254*b_enc + colsum(pos)
//   400  : bW[16]      = W_enc @ b_enc
//   416  : bK[1]       = b_enc . K
//   432  : G[254*16]   = pos @ W_enc^T  ([n*16+l])
//   4496 : pK[254]     = pos @ K
//   4752 : Kpart[16*128] partial column sums of pos
#define WS_M    128
#define WS_VK   384
#define WS_BW   400
#define WS_BK   416
#define WS_G    432
#define WS_PK   4496
#define WS_KP   4752

// ---- stage 1: partial column sums of pos (254 x 128), coalesced ----
__global__ __launch_bounds__(256) void preK(const float* __restrict__ pos,
                                            float* __restrict__ ws) {
    __shared__ float red[256];
    int t = threadIdx.x;
    int h = t & 127, j = t >> 7;          // j in {0,1}
    int n0 = blockIdx.x * 16;             // 16 blocks x 16 rows (last: 14)
    float acc = 0.f;
    #pragma unroll
    for (int r = 0; r < 8; r++) {
        int n = n0 + j + 2 * r;
        if (n < N_) acc += pos[n * H_ + h];
    }
    red[t] = acc;
    __syncthreads();
    if (t < 128) ws[WS_KP + blockIdx.x * 128 + t] = red[t] + red[t + 128];
}

// ---- stage 2: G,pK (blocks 0..253) + M,vK,bW,bK (block 254) ----
__global__ __launch_bounds__(128) void pre2b(const float* __restrict__ W_enc,
                                             const float* __restrict__ b_enc,
                                             const float* __restrict__ pos,
                                             float* __restrict__ ws) {
    __shared__ float Ks[128], bL[128], pLDS[128], red[128], red2[128];
    __shared__ float WL[2048];
    int t = threadIdx.x;                  // 128 threads
    int n = blockIdx.x;                   // 0..254

    // rebuild K locally (L2-hot partials): K[h] = 254*b_enc[h] + sum_g part
    {
        float b = b_enc[t];
        float s = 254.f * b;
        #pragma unroll
        for (int g = 0; g < 16; g++) s += ws[WS_KP + g * 128 + t];
        Ks[t] = s;
        bL[t] = b;
    }

    if (n < N_) {
        pLDS[t] = pos[n * H_ + t];
        __syncthreads();
        // G partials: t -> (l = t>>3, c = t&7), 16-wide h-chunk each
        {
            int l = t >> 3, c = t & 7;
            const float* w = W_enc + l * H_ + c * 16;
            const float* p = pLDS + c * 16;
            float s = 0.f;
            #pragma unroll
            for (int i = 0; i < 16; i++) s += p[i] * w[i];
            red[t] = s;
            red2[t] = pLDS[t] * Ks[t];
        }
        __syncthreads();
        if (t < 16) {                     // G final
            float s = 0.f;
            #pragma unroll
            for (int c = 0; c < 8; c++) s += red[t * 8 + c];
            ws[WS_G + n * 16 + t] = s;
        }
        if (t >= 64) {                    // pK final (wave 1)
            int lane = t - 64;
            float s = red2[lane] + red2[lane + 64];
            for (int off = 32; off; off >>= 1) s += __shfl_down(s, off);
            if (lane == 0) ws[WS_PK + n] = s;
        }
    } else {
        // block 254: stage W_enc (16x128) into LDS, then tiny dots
        for (int i = t; i < 512; i += 128) {
            float4 v = ((const float4*)W_enc)[i];
            float* p = &WL[i * 4];
            p[0] = v.x; p[1] = v.y; p[2] = v.z; p[3] = v.w;
        }
        __syncthreads();
        #pragma unroll
        for (int e0 = 0; e0 < 2; e0++) {  // M: 256 entries / 128 threads
            int e = e0 * 128 + t;
            int l1 = e >> 4, l2 = e & 15;
            float s = 0.f;
            for (int h = 0; h < H_; h++) s += WL[l1 * H_ + h] * WL[l2 * H_ + h];
            ws[WS_M + e] = s;
        }
        if (t < 16) {
            float s1 = 0.f, s2 = 0.f;
            for (int h = 0; h < H_; h++) {
                float w = WL[t * H_ + h];
                s1 += w * Ks[h];
                s2 += w * bL[h];
            }
            ws[WS_VK + t] = s1;
            ws[WS_BW + t] = s2;
        }
        if (t == 16) {
            float s = 0.f;
            for (int h = 0; h < H_; h++) s += bL[h] * Ks[h];
            ws[WS_BK] = s;
        }
    }
}

__global__ __launch_bounds__(256) void mainker(const float* __restrict__ x,
                                               const float* __restrict__ W1,
                                               const float* __restrict__ b1,
                                               const float* __restrict__ W2,
                                               const float* __restrict__ b2,
                                               const float* __restrict__ ws,
                                               float* __restrict__ out) {
    __shared__ float xf[N_ * 17 + 16];  // stride-17 padded x tile
    __shared__ float red[256];
    __shared__ float scoreS[N_];
    __shared__ float xsS[16], vS[16], pooledS[16], hS[128];
    __shared__ float s0S, denomS;

    int t  = threadIdx.x;
    int bd = blockIdx.x;   // b*64 + d

    // ---- load x slice (4064 floats = 1016 float4), write copy, unpack to LDS ----
    const float4* xv = (const float4*)(x + (size_t)bd * XPAIR);
    float4*       cv = (float4*)(out + OUT0) + (size_t)bd * (XPAIR / 4);
    for (int i = t; i < XPAIR / 4; i += 256) {
        float4 v = xv[i];
        cv[i] = v;
        int idx = i * 4;                 // idx%16 in {0,4,8,12}: no row crossing
        int n = idx >> 4, l = idx & 15;
        float* p = &xf[n * 17 + l];
        p[0] = v.x; p[1] = v.y; p[2] = v.z; p[3] = v.w;
    }
    __syncthreads();

    // ---- xs[l] = sum_n x[n,l] ----
    {
        int l = t & 15, g = t >> 4;
        float s = 0.f;
        for (int n = g; n < N_; n += 16) s += xf[n * 17 + l];
        red[t] = s;
    }
    __syncthreads();
    if (t < 16) {
        float s = 0.f;
        for (int g = 0; g < 16; g++) s += red[g * 16 + t];
        xsS[t] = s;
    }
    __syncthreads();

    // ---- v[l] = vK[l] + (M^T xs)[l];  s0 = bK + xs.bW ----
    if (t < 16) {
        float s = ws[WS_VK + t];
        for (int l2 = 0; l2 < 16; l2++) s += xsS[l2] * ws[WS_M + l2 * 16 + t];
        vS[t] = s;
    } else if (t == 16) {
        float s = ws[WS_BK];
        for (int l = 0; l < 16; l++) s += xsS[l] * ws[WS_BW + l];
        s0S = s;
    }
    __syncthreads();

    // ---- score[n] = s0 + pK[n] + x[n].v + xs.G[n] ----
    if (t < N_) {
        const float* Gn = ws + WS_G + t * 16;
        float s = s0S + ws[WS_PK + t];
        #pragma unroll
        for (int l = 0; l < 16; l++) s += xf[t * 17 + l] * vS[l] + xsS[l] * Gn[l];
        scoreS[t] = s;
    }
    __syncthreads();

    // ---- denom = sum |score| (wave 0) ----
    if (t < 64) {
        float s = 0.f;
        for (int n = t; n < N_; n += 64) s += fabsf(scoreS[n]);
        for (int off = 32; off; off >>= 1) s += __shfl_down(s, off);
        if (t == 0) denomS = s;
    }
    __syncthreads();
    float inv = 1.0f / denomS;

    // ---- pooled[l] = (sum_n x[n,l]*score[n]) / denom ----
    {
        int l = t & 15, g = t >> 4;
        float s = 0.f;
        for (int n = g; n < N_; n += 16) s += xf[n * 17 + l] * scoreS[n];
        red[t] = s;
    }
    __syncthreads();
    if (t < 16) {
        float s = 0.f;
        for (int g = 0; g < 16; g++) s += red[g * 16 + t];
        pooledS[t] = s * inv;
    }
    __syncthreads();

    // ---- h = leaky_relu(pooled @ W1 + b1, 0.2) ----
    if (t < 128) {
        float s = b1[t];
        #pragma unroll
        for (int l = 0; l < 16; l++) s += pooledS[l] * W1[l * H_ + t];
        hS[t] = s > 0.f ? s : 0.2f * s;
    }
    __syncthreads();

    // ---- out0[b, p, d] = h @ W2 + b2 ----
    if (t < 96) {
        float s = b2[t];
        for (int j = 0; j < 128; j++) s += hS[j] * W2[j * P_ + t];
        int b = bd >> 6, d = bd & 63;
        out[b * (P_ * D_) + t * D_ + d] = s;
    }
}

extern "C" void kernel_launch(void* const* d_in, const int* in_sizes, int n_in,
                              void* d_out, int out_size, void* d_ws, size_t ws_size,
                              hipStream_t stream) {
    const float* x     = (const float*)d_in[0];
    const float* W_enc = (const float*)d_in[1];
    const float* b_enc = (const float*)d_in[2];
    const float* W1    = (const float*)d_in[3];
    const float* b1    = (const float*)d_in[4];
    const float* W2    = (const float*)d_in[5];
    const float* b2    = (const float*)d_in[6];
    const float* pos   = (const float*)d_in[7];
    float* ws  = (float*)d_ws;
    float* out = (float*)d_out;

    hipLaunchKernelGGL(preK,   dim3(16),    dim3(256), 0, stream, pos, ws);
    hipLaunchKernelGGL(pre2b,  dim3(255),   dim3(128), 0, stream, W_enc, b_enc, pos, ws);
    hipLaunchKernelGGL(mainker, dim3(PAIRS), dim3(256), 0, stream, x, W1, b1, W2, b2, ws, out);
}